// Round 1
// baseline (92.867 us; speedup 1.0000x reference)
//
#include <hip/hip_runtime.h>
#include <math.h>

#define BB 16
#define SP1 513
#define SS 512
#define VV 32000
#define NROWS (BB * SS)
#define THREADS 256

// One block per (b, s) output row. Early-exit on masked rows (≈50% of them),
// single-pass online softmax-denominator over V=32000 with float4 loads.
__global__ __launch_bounds__(THREADS) void ce_row_kernel(
    const float* __restrict__ logits,   // (B, SP1, V)
    const int* __restrict__ trg,        // (B, SP1)
    const int* __restrict__ lengths,    // (B,)
    float* __restrict__ row_loss,       // (NROWS,)
    int* __restrict__ row_valid)        // (NROWS,)
{
    const int row = blockIdx.x;       // 0 .. NROWS-1
    const int b = row >> 9;           // / 512
    const int s = row & 511;          // % 512

    const int tgt = trg[b * SP1 + (s + 1)];
    const bool valid = (s < lengths[b]) && (tgt != 0);
    if (!valid) {
        if (threadIdx.x == 0) { row_loss[row] = 0.0f; row_valid[row] = 0; }
        return;
    }

    const float* rowp = logits + ((size_t)b * SP1 + (s + 1)) * VV;
    const float4* rp4 = reinterpret_cast<const float4*>(rowp);

    // Online (max, sum-exp) over this thread's strided slice.
    float m = -1e30f;
    float sum = 0.0f;
    for (int i = threadIdx.x; i < VV / 4; i += THREADS) {
        float4 v = rp4[i];
        float mx = fmaxf(fmaxf(v.x, v.y), fmaxf(v.z, v.w));
        float nm = fmaxf(m, mx);
        sum = sum * __expf(m - nm)
            + __expf(v.x - nm) + __expf(v.y - nm)
            + __expf(v.z - nm) + __expf(v.w - nm);
        m = nm;
    }

    // Wave (64-lane) reduction of (m, sum).
    #pragma unroll
    for (int off = 32; off > 0; off >>= 1) {
        float om = __shfl_down(m, off);
        float os = __shfl_down(sum, off);
        float nm = fmaxf(m, om);
        sum = sum * __expf(m - nm) + os * __expf(om - nm);
        m = nm;
    }

    // Cross-wave reduction via LDS (4 waves).
    __shared__ float sm[THREADS / 64];
    __shared__ float ssum[THREADS / 64];
    const int wave = threadIdx.x >> 6;
    const int lane = threadIdx.x & 63;
    if (lane == 0) { sm[wave] = m; ssum[wave] = sum; }
    __syncthreads();

    if (threadIdx.x == 0) {
        float M = sm[0];
        float Ssum = ssum[0];
        #pragma unroll
        for (int w = 1; w < THREADS / 64; ++w) {
            float nm = fmaxf(M, sm[w]);
            Ssum = Ssum * __expf(M - nm) + ssum[w] * __expf(sm[w] - nm);
            M = nm;
        }
        const float xt = rowp[tgt];      // L2-hot: this row was just streamed
        row_loss[row] = (M + logf(Ssum)) - xt;   // -log_softmax[tgt]
        row_valid[row] = 1;
    }
}

// Deterministic final reduction: single block, fixed order.
__global__ __launch_bounds__(THREADS) void ce_final_kernel(
    const float* __restrict__ row_loss,
    const int* __restrict__ row_valid,
    float* __restrict__ out)
{
    float s = 0.0f;
    int n = 0;
    for (int i = threadIdx.x; i < NROWS; i += THREADS) {
        s += row_loss[i];
        n += row_valid[i];
    }
    #pragma unroll
    for (int off = 32; off > 0; off >>= 1) {
        s += __shfl_down(s, off);
        n += __shfl_down(n, off);
    }
    __shared__ float sl[THREADS / 64];
    __shared__ int sn[THREADS / 64];
    const int wave = threadIdx.x >> 6;
    const int lane = threadIdx.x & 63;
    if (lane == 0) { sl[wave] = s; sn[wave] = n; }
    __syncthreads();
    if (threadIdx.x == 0) {
        float ts = 0.0f;
        int tn = 0;
        #pragma unroll
        for (int w = 0; w < THREADS / 64; ++w) { ts += sl[w]; tn += sn[w]; }
        out[0] = ts / (float)(tn > 0 ? tn : 1);
    }
}

extern "C" void kernel_launch(void* const* d_in, const int* in_sizes, int n_in,
                              void* d_out, int out_size, void* d_ws, size_t ws_size,
                              hipStream_t stream) {
    const float* logits  = (const float*)d_in[0];
    const int*   trg     = (const int*)d_in[1];
    const int*   lengths = (const int*)d_in[2];

    float* row_loss  = (float*)d_ws;
    int*   row_valid = (int*)((char*)d_ws + NROWS * sizeof(float));

    ce_row_kernel<<<NROWS, THREADS, 0, stream>>>(logits, trg, lengths, row_loss, row_valid);
    ce_final_kernel<<<1, THREADS, 0, stream>>>(row_loss, row_valid, (float*)d_out);
}